// Round 5
// baseline (262.674 us; speedup 1.0000x reference)
//
#include <hip/hip_runtime.h>
#include <hip/hip_bf16.h>
#include <cmath>

// Problem constants (from reference)
#define N_TOK 32768
#define KDIM  1024
#define ODIM  1024

// GEMM tile: 256x128 block, BK=64, 8 waves duty-split:
//   waves 0-3: mean GEMM (x @ Wm^T), waves 4-7: var GEMM (x^2 @ Wv^T)
// Wave-tile 128x64 (8x4 frags of 16x16x32). LDS dbuf 2 x 64KB.
// Schedule: counted-vmcnt pipeline (T3/T4), raw s_barrier, setprio (T5).
#define BM 256
#define BN 128
#define BK 64
#define NKT (KDIM / BK)   // 16 k-tiles
#define THREADS 512
#define BUFSZ 65536

typedef float          f32x4  __attribute__((ext_vector_type(4)));
typedef __bf16         bf16x8 __attribute__((ext_vector_type(8)));
typedef unsigned short us8    __attribute__((ext_vector_type(8)));
typedef unsigned short us2    __attribute__((ext_vector_type(2)));

#define VMCNT(n)  asm volatile("s_waitcnt vmcnt(" #n ")" ::: "memory")
#define LGKM0()   asm volatile("s_waitcnt lgkmcnt(0)" ::: "memory")
#define SBAR()    asm volatile("s_barrier" ::: "memory")
#define SCHED0()  __builtin_amdgcn_sched_barrier(0)

// round-to-nearest-even f32 -> bf16 (prep kernel only)
static __device__ __forceinline__ unsigned short f2bf(float f) {
  unsigned u = __builtin_bit_cast(unsigned, f);
  u += 0x7FFFu + ((u >> 16) & 1u);
  return (unsigned short)(u >> 16);
}

static __device__ __forceinline__ unsigned short bfc(float f) {
  return __builtin_bit_cast(unsigned short, (__bf16)f);
}

static __device__ __forceinline__ f32x4 mfma16(us8 a, us8 b, f32x4 c) {
  return __builtin_amdgcn_mfma_f32_16x16x32_bf16(
      __builtin_bit_cast(bf16x8, a), __builtin_bit_cast(bf16x8, b), c, 0, 0, 0);
}

static __device__ __forceinline__ void gl_lds16(const void* g, void* l) {
  __builtin_amdgcn_global_load_lds(
      (const __attribute__((address_space(1))) void*)g,
      (__attribute__((address_space(3))) void*)l, 16, 0, 0);
}

// elementwise square of 8 bf16 (exact f32 product, RNE repack)
static __device__ __forceinline__ us8 sqr8(us8 a) {
  us8 r;
#pragma unroll
  for (int i = 0; i < 8; ++i) {
    float f = __builtin_bit_cast(float, (unsigned)a[i] << 16);
    r[i] = bfc(f * f);
  }
  return r;
}

// ---------------------------------------------------------------------------
// Prep: weight_logits [O][I][2] (mag,sgn interleaved) -> bf16 W_mean, W_var
// ---------------------------------------------------------------------------
__global__ void wprep_kernel(const float* __restrict__ wl,
                             unsigned short* __restrict__ wm,
                             unsigned short* __restrict__ wv) {
  int i = blockIdx.x * blockDim.x + threadIdx.x;       // 2 elems each
  f32x4 v = *reinterpret_cast<const f32x4*>(wl + (size_t)i * 4);
  float pm0 = 1.f / (1.f + expf(-v.x));
  float ps0 = 1.f / (1.f + expf(-v.y));
  float pm1 = 1.f / (1.f + expf(-v.z));
  float ps1 = 1.f / (1.f + expf(-v.w));
  float m0 = pm0 * (2.f * ps0 - 1.f);
  float m1 = pm1 * (2.f * ps1 - 1.f);
  float q0 = pm0 - m0 * m0;
  float q1 = pm1 - m1 * m1;
  us2 am = {f2bf(m0), f2bf(m1)};
  us2 av = {f2bf(q0), f2bf(q1)};
  *reinterpret_cast<us2*>(wm + (size_t)i * 2) = am;
  *reinterpret_cast<us2*>(wv + (size_t)i * 2) = av;
}

// ---------------------------------------------------------------------------
__global__ __launch_bounds__(THREADS, 2) void ternary_gemm(
    const float* __restrict__ x,
    const unsigned short* __restrict__ wm,
    const unsigned short* __restrict__ wv,
    const float* __restrict__ scale,
    const float* __restrict__ shift,
    const float* __restrict__ noise,
    float* __restrict__ out) {
  __shared__ alignas(16) char smem[2 * BUFSZ];
  // per buffer: AsX [256][64] bf16 at +0 (32K), BsM [128][64] at +32K,
  //             BsV [128][64] at +48K. XOR-swizzled: byte ^= (row&7)<<4.

  const int tid  = threadIdx.x;
  const int lane = tid & 63;
  const int w    = tid >> 6;
  const bool isVar = (w >= 4);     // waves 0-3 mean / 4-7 var; SIMD i gets 1 of each
  const int p    = w & 3;
  const int wr   = p >> 1;
  const int wc   = p & 1;
  const int l15  = lane & 15;
  const int l4   = lane >> 4;

  // XCD-bijective swizzle (1024 blocks % 8 == 0), bn-inner per XCD
  const int bid = blockIdx.x;
  const int swz = (bid & 7) * 128 + (bid >> 3);
  const int bm  = swz >> 3;
  const int bn  = swz & 7;
  const int rowBase = bm * BM;
  const int colBase = bn * BN;

  f32x4 acc[8][4];
#pragma unroll
  for (int i = 0; i < 8; ++i)
#pragma unroll
    for (int j = 0; j < 4; ++j) acc[i][j] = (f32x4)0.f;

  const float* xb = x + (size_t)rowBase * KDIM;

  // ---- staging helpers -----------------------------------------------------
  auto stageB = [&](int kt, char* buf) {       // 4 gl_lds / thread
    const int k0 = kt * BK;
    char* BsM = buf + 32768;
    char* BsV = buf + 49152;
#pragma unroll
    for (int c = 0; c < 2; ++c) {
      int flat = c * THREADS + tid;        // 0..1023
      int row  = flat >> 3;                // 0..127
      int j    = flat & 7;
      size_t goff = (size_t)(colBase + row) * KDIM + k0 + ((j ^ (row & 7)) << 3);
      gl_lds16(wm + goff, BsM + flat * 16);
      gl_lds16(wv + goff, BsV + flat * 16);
    }
  };
  auto loadX = [&](int kt, f32x4* ap) {        // 8 global_load_dwordx4 / thread
    const float* xt = xb + kt * BK;
#pragma unroll
    for (int c = 0; c < 4; ++c) {
      int flat = c * THREADS + tid;        // 0..2047
      int row  = flat >> 3;                // 0..255
      int j    = flat & 7;
      const float* s = xt + (size_t)row * KDIM + j * 8;
      ap[2 * c]     = *reinterpret_cast<const f32x4*>(s);
      ap[2 * c + 1] = *reinterpret_cast<const f32x4*>(s + 4);
    }
  };
  auto writeA = [&](const f32x4* ap, char* buf) {  // 4 ds_write_b128 / thread
#pragma unroll
    for (int c = 0; c < 4; ++c) {
      int flat = c * THREADS + tid;
      int row  = flat >> 3;
      int j    = flat & 7;
      f32x4 v0 = ap[2 * c], v1 = ap[2 * c + 1];
      us8 o = {bfc(v0.x), bfc(v0.y), bfc(v0.z), bfc(v0.w),
               bfc(v1.x), bfc(v1.y), bfc(v1.z), bfc(v1.w)};
      int off = row * 128 + ((j * 16) ^ ((row & 7) << 4));
      *reinterpret_cast<us8*>(buf + off) = o;
    }
  };

  // ---- prologue: stage tile 0 (order: loadX first, then gl_lds) -----------
  f32x4 ap[8];
  loadX(0, ap);
  stageB(0, smem);
  VMCNT(4);             // loadX(0) done (oldest 8); stageB(0) still in flight
  SCHED0();
  writeA(ap, smem);
  LGKM0();
  SBAR();

  // ---- main loop ----------------------------------------------------------
  for (int kt = 0; kt < NKT; ++kt) {
    const char* cur = smem + (size_t)(kt & 1) * BUFSZ;
    char*       nxt = smem + (size_t)((kt + 1) & 1) * BUFSZ;

    // issue next tile's loads; they stay in flight across barriers
    if (kt + 1 < NKT) {
      loadX(kt + 1, ap);            // 8 (issued first)
      stageB(kt + 1, nxt);          // 4 gl_lds
      VMCNT(12);                    // waits stageB(kt) (oldest 4 of 16)
    } else {
      VMCNT(0);
    }
    SCHED0();

    const char* Ab = cur;
    const char* Bb = cur + 32768 + (isVar ? 16384 : 0);

    us8 bf_[4];
#pragma unroll
    for (int ks = 0; ks < 2; ++ks) {
      const int kb = ks * 64 + (l4 << 4);
      // --- phase (ks, ih=0): load B frags + A[0..3], 16 MFMA
#pragma unroll
      for (int b = 0; b < 4; ++b) {
        int row = wc * 64 + b * 16 + l15;
        bf_[b] = *reinterpret_cast<const us8*>(Bb + row * 128 + (kb ^ ((row & 7) << 4)));
      }
#pragma unroll
      for (int ih = 0; ih < 2; ++ih) {
        us8 af[4];
#pragma unroll
        for (int ii = 0; ii < 4; ++ii) {
          int row = wr * 128 + (ih * 4 + ii) * 16 + l15;
          af[ii] = *reinterpret_cast<const us8*>(Ab + row * 128 + (kb ^ ((row & 7) << 4)));
        }
        if (isVar) {
#pragma unroll
          for (int ii = 0; ii < 4; ++ii) af[ii] = sqr8(af[ii]);
        }
        __builtin_amdgcn_s_setprio(1);
#pragma unroll
        for (int ii = 0; ii < 4; ++ii)
#pragma unroll
          for (int b = 0; b < 4; ++b)
            acc[ih * 4 + ii][b] = mfma16(af[ii], bf_[b], acc[ih * 4 + ii][b]);
        __builtin_amdgcn_s_setprio(0);
        SBAR();                      // bare barrier: no counter drain
      }
    }

    // convert + write A(kt+1) into nxt
    if (kt + 1 < NKT) {
      VMCNT(4);                     // waits loadX(kt+1) (oldest 8 of 12)
      SCHED0();
      writeA(ap, nxt);
    }
    LGKM0();                        // ds_writes visible before barrier
    SBAR();
  }

  // ---- epilogue: cross-wave exchange, 128KB, 2-way max --------------------
  float* Mx = (float*)smem;             // [4][64][64] f32, col ^ ((lr&4)<<2)
  float* Vx = (float*)(smem + 65536);
  if (!isVar) {
#pragma unroll
    for (int i = 4; i < 8; ++i)
#pragma unroll
      for (int b = 0; b < 4; ++b)
#pragma unroll
        for (int j = 0; j < 4; ++j) {
          int lr = (i - 4) * 16 + l4 * 4 + j;
          int lc = b * 16 + l15;
          Mx[(p * 64 + lr) * 64 + (lc ^ ((lr & 4) << 2))] = acc[i][b][j];
        }
  } else {
#pragma unroll
    for (int i = 0; i < 4; ++i)
#pragma unroll
      for (int b = 0; b < 4; ++b)
#pragma unroll
        for (int j = 0; j < 4; ++j) {
          int lr = i * 16 + l4 * 4 + j;
          int lc = b * 16 + l15;
          Vx[(p * 64 + lr) * 64 + (lc ^ ((lr & 4) << 2))] = acc[i][b][j];
        }
  }
  __syncthreads();

  if (!isVar) {
#pragma unroll
    for (int i = 0; i < 4; ++i)
#pragma unroll
      for (int b = 0; b < 4; ++b) {
        int col = colBase + wc * 64 + b * 16 + l15;
        float sc = scale[col], sh = shift[col];
#pragma unroll
        for (int j = 0; j < 4; ++j) {
          int lr = i * 16 + l4 * 4 + j;
          float vv = Vx[(p * 64 + lr) * 64 + ((b * 16 + l15) ^ ((lr & 4) << 2))];
          size_t idx = (size_t)(rowBase + wr * 128 + lr) * ODIM + col;
          out[idx] = fmaf(acc[i][b][j] + sqrtf(fmaxf(vv, 0.f)) * noise[idx], sc, sh);
        }
      }
  } else {
#pragma unroll
    for (int i = 4; i < 8; ++i)
#pragma unroll
      for (int b = 0; b < 4; ++b) {
        int col = colBase + wc * 64 + b * 16 + l15;
        float sc = scale[col], sh = shift[col];
#pragma unroll
        for (int j = 0; j < 4; ++j) {
          int lr = (i - 4) * 16 + l4 * 4 + j;
          float mm = Mx[(p * 64 + lr) * 64 + ((b * 16 + l15) ^ ((lr & 4) << 2))];
          size_t idx = (size_t)(rowBase + wr * 128 + 64 + lr) * ODIM + col;
          out[idx] = fmaf(mm + sqrtf(fmaxf(acc[i][b][j], 0.f)) * noise[idx], sc, sh);
        }
      }
  }
}

// ---------------------------------------------------------------------------
extern "C" void kernel_launch(void* const* d_in, const int* in_sizes, int n_in,
                              void* d_out, int out_size, void* d_ws, size_t ws_size,
                              hipStream_t stream) {
  const float* x     = (const float*)d_in[0];   // [32768,1024]
  const float* wl    = (const float*)d_in[1];   // [1024,1024,2]
  const float* scale = (const float*)d_in[2];   // [1024]
  const float* shift = (const float*)d_in[3];   // [1024]
  const float* noise = (const float*)d_in[4];   // [32768,1024]
  float* out = (float*)d_out;

  unsigned short* wm = (unsigned short*)d_ws;            // [1024][1024] bf16
  unsigned short* wv = wm + (size_t)ODIM * KDIM;         // [1024][1024] bf16

  wprep_kernel<<<(ODIM * KDIM / 2) / 256, 256, 0, stream>>>(wl, wm, wv);

  // grid = (32768/256) * (1024/128) = 1024 blocks of 512 threads
  ternary_gemm<<<(N_TOK / BM) * (ODIM / BN), THREADS, 0, stream>>>(
      x, wm, wv, scale, shift, noise, out);
}

// Round 6
// 233.213 us; speedup vs baseline: 1.1263x; 1.1263x over previous
//
#include <hip/hip_runtime.h>
#include <hip/hip_bf16.h>
#include <cmath>

// Problem constants (from reference)
#define N_TOK 32768
#define KDIM  1024
#define ODIM  1024

// GEMM tile: 128x128 block, BK=64, 8 waves duty-split:
//   waves 0-3: mean GEMM, waves 4-7: var GEMM (square bf16 A-frags in-register)
// All staging via global_load_lds (x pre-converted to bf16 in ws).
// LDS 48KB single-buffered -> 2 blocks/CU; m97 2-barrier loop.
#define BM 128
#define BN 128
#define BK 64
#define NKT (KDIM / BK)   // 16 k-tiles
#define THREADS 512

typedef float          f32x4  __attribute__((ext_vector_type(4)));
typedef __bf16         bf16x8 __attribute__((ext_vector_type(8)));
typedef unsigned short us8    __attribute__((ext_vector_type(8)));
typedef unsigned short us2    __attribute__((ext_vector_type(2)));

// round-to-nearest-even f32 -> bf16
static __device__ __forceinline__ unsigned short f2bf(float f) {
  unsigned u = __builtin_bit_cast(unsigned, f);
  u += 0x7FFFu + ((u >> 16) & 1u);
  return (unsigned short)(u >> 16);
}
static __device__ __forceinline__ unsigned short bfc(float f) {
  return __builtin_bit_cast(unsigned short, (__bf16)f);
}
static __device__ __forceinline__ float bf2f(unsigned short u) {
  return __builtin_bit_cast(float, (unsigned)u << 16);
}

static __device__ __forceinline__ f32x4 mfma16(us8 a, us8 b, f32x4 c) {
  return __builtin_amdgcn_mfma_f32_16x16x32_bf16(
      __builtin_bit_cast(bf16x8, a), __builtin_bit_cast(bf16x8, b), c, 0, 0, 0);
}

static __device__ __forceinline__ void gl_lds16(const void* g, void* l) {
  __builtin_amdgcn_global_load_lds(
      (const __attribute__((address_space(1))) void*)g,
      (__attribute__((address_space(3))) void*)l, 16, 0, 0);
}

// elementwise square of 8 bf16 (f32 product, RNE repack) — verified in R4
static __device__ __forceinline__ us8 sqr8(us8 a) {
  us8 r;
#pragma unroll
  for (int i = 0; i < 8; ++i) {
    float f = bf2f(a[i]);
    r[i] = bfc(f * f);
  }
  return r;
}

// ---------------------------------------------------------------------------
// Prep 1: weight_logits [O][I][2] -> bf16 W_mean, W_var
// ---------------------------------------------------------------------------
__global__ void wprep_kernel(const float* __restrict__ wl,
                             unsigned short* __restrict__ wm,
                             unsigned short* __restrict__ wv) {
  int i = blockIdx.x * blockDim.x + threadIdx.x;       // 2 elems each
  f32x4 v = *reinterpret_cast<const f32x4*>(wl + (size_t)i * 4);
  float pm0 = 1.f / (1.f + expf(-v.x));
  float ps0 = 1.f / (1.f + expf(-v.y));
  float pm1 = 1.f / (1.f + expf(-v.z));
  float ps1 = 1.f / (1.f + expf(-v.w));
  float m0 = pm0 * (2.f * ps0 - 1.f);
  float m1 = pm1 * (2.f * ps1 - 1.f);
  float q0 = pm0 - m0 * m0;
  float q1 = pm1 - m1 * m1;
  us2 am = {f2bf(m0), f2bf(m1)};
  us2 av = {f2bf(q0), f2bf(q1)};
  *reinterpret_cast<us2*>(wm + (size_t)i * 2) = am;
  *reinterpret_cast<us2*>(wv + (size_t)i * 2) = av;
}

// ---------------------------------------------------------------------------
// Prep 2: x f32 [32768][1024] -> bf16 (row-major, same layout)
// 4,194,304 us8-chunks; 1,048,576 threads x 4 chunks.
// ---------------------------------------------------------------------------
__global__ void xprep_kernel(const float* __restrict__ x,
                             unsigned short* __restrict__ xbf) {
  const int t = blockIdx.x * blockDim.x + threadIdx.x;
#pragma unroll
  for (int i = 0; i < 4; ++i) {
    size_t c = (size_t)i * 1048576 + t;
    const float* s = x + c * 8;
    f32x4 v0 = *reinterpret_cast<const f32x4*>(s);
    f32x4 v1 = *reinterpret_cast<const f32x4*>(s + 4);
    us8 o = {bfc(v0.x), bfc(v0.y), bfc(v0.z), bfc(v0.w),
             bfc(v1.x), bfc(v1.y), bfc(v1.z), bfc(v1.w)};
    *reinterpret_cast<us8*>(xbf + c * 8) = o;
  }
}

// ---------------------------------------------------------------------------
// Dual GEMM + fused epilogue.  PRE: x pre-converted (all-DMA staging).
// LDS per k-tile: AsX[128][64]@0 | BsM@16K | BsV@32K, all byte^=(row&7)<<4.
// ---------------------------------------------------------------------------
template <bool PRE>
__global__ __launch_bounds__(THREADS, 2) void ternary_gemm(
    const float* __restrict__ x,
    const unsigned short* __restrict__ xbf,
    const unsigned short* __restrict__ wm,
    const unsigned short* __restrict__ wv,
    const float* __restrict__ scale,
    const float* __restrict__ shift,
    const float* __restrict__ noise,
    float* __restrict__ out) {
  __shared__ alignas(16) char smem[49152];

  const int tid  = threadIdx.x;
  const int lane = tid & 63;
  const int w    = tid >> 6;       // 0..7
  const bool isVar = (w >= 4);
  const int p    = w & 3;          // region id (2x2 grid of 64x64)
  const int wr   = p >> 1;
  const int wc   = p & 1;
  const int l15  = lane & 15;
  const int l4   = lane >> 4;

  // XCD-bijective swizzle (2048 blocks % 8 == 0), bn-inner per XCD
  const int bid = blockIdx.x;
  const int swz = (bid & 7) * 256 + (bid >> 3);
  const int bm  = swz >> 3;        // 0..255
  const int bn  = swz & 7;         // 0..7
  const int rowBase = bm * BM;
  const int colBase = bn * BN;

  f32x4 acc[4][4];
#pragma unroll
  for (int i = 0; i < 4; ++i)
#pragma unroll
    for (int j = 0; j < 4; ++j) acc[i][j] = (f32x4)0.f;

  for (int kt = 0; kt < NKT; ++kt) {
    const int k0 = kt * BK;

    // ---- stage B (Wm, Wv): 4 gl_lds/thread, linear dest, inv-swizzled src
#pragma unroll
    for (int c = 0; c < 2; ++c) {
      int flat = c * THREADS + tid;      // 0..1023 16B chunks
      int row  = flat >> 3;              // 0..127
      int j    = flat & 7;
      size_t go = (size_t)(colBase + row) * KDIM + k0 + ((j ^ (row & 7)) << 3);
      gl_lds16(wm + go, smem + 16384 + flat * 16);
      gl_lds16(wv + go, smem + 32768 + flat * 16);
    }
    // ---- stage A (x bf16)
    if constexpr (PRE) {
#pragma unroll
      for (int c = 0; c < 2; ++c) {
        int flat = c * THREADS + tid;
        int row  = flat >> 3;
        int j    = flat & 7;
        size_t go = (size_t)(rowBase + row) * KDIM + k0 + ((j ^ (row & 7)) << 3);
        gl_lds16(xbf + go, smem + flat * 16);
      }
    } else {
      // fallback: f32 load + convert + swizzled ds_write
#pragma unroll
      for (int c = 0; c < 2; ++c) {
        int flat = c * THREADS + tid;
        int row  = flat >> 3;
        int j    = flat & 7;
        const float* s = x + (size_t)(rowBase + row) * KDIM + k0 + j * 8;
        f32x4 v0 = *reinterpret_cast<const f32x4*>(s);
        f32x4 v1 = *reinterpret_cast<const f32x4*>(s + 4);
        us8 o = {bfc(v0.x), bfc(v0.y), bfc(v0.z), bfc(v0.w),
                 bfc(v1.x), bfc(v1.y), bfc(v1.z), bfc(v1.w)};
        int off = row * 128 + ((j * 16) ^ ((row & 7) << 4));
        *reinterpret_cast<us8*>(smem + off) = o;
      }
    }
    __syncthreads();   // drains DMA (vmcnt) + any ds_writes

    // ---- compute: 2 k-steps, 4x4 frags, single GEMM per wave
    const char* Bb = smem + 16384 + (isVar ? 16384 : 0);
#pragma unroll
    for (int ks = 0; ks < 2; ++ks) {
      const int kb = ks * 64 + (l4 << 4);
      us8 bfr[4], afr[4];
#pragma unroll
      for (int b = 0; b < 4; ++b) {
        int row = wc * 64 + b * 16 + l15;
        bfr[b] = *reinterpret_cast<const us8*>(Bb + row * 128 + (kb ^ ((row & 7) << 4)));
      }
#pragma unroll
      for (int a = 0; a < 4; ++a) {
        int row = wr * 64 + a * 16 + l15;
        afr[a] = *reinterpret_cast<const us8*>(smem + row * 128 + (kb ^ ((row & 7) << 4)));
        if (isVar) afr[a] = sqr8(afr[a]);
      }
      __builtin_amdgcn_s_setprio(1);
#pragma unroll
      for (int a = 0; a < 4; ++a)
#pragma unroll
        for (int b = 0; b < 4; ++b)
          acc[a][b] = mfma16(afr[a], bfr[b], acc[a][b]);
      __builtin_amdgcn_s_setprio(0);
    }
    __syncthreads();   // staging LDS free for next k-tile
  }

  // ---- epilogue: bf16 cross-wave exchange (32KB), XOR'd conflict-free.
  // mean wave p ships M rows 32..63 of its region; var ships V rows 0..31.
  unsigned short* MxB = (unsigned short*)smem;            // [4][32][64]
  unsigned short* VxB = (unsigned short*)(smem + 16384);  // [4][32][64]
  if (!isVar) {
#pragma unroll
    for (int i = 2; i < 4; ++i)
#pragma unroll
      for (int b = 0; b < 4; ++b)
#pragma unroll
        for (int j = 0; j < 4; ++j) {
          int lr = (i - 2) * 16 + l4 * 4 + j;   // 0..31
          int lc = b * 16 + l15;
          MxB[(p * 32 + lr) * 64 + (lc ^ (((lr >> 2) & 3) << 4))] = bfc(acc[i][b][j]);
        }
  } else {
#pragma unroll
    for (int i = 0; i < 2; ++i)
#pragma unroll
      for (int b = 0; b < 4; ++b)
#pragma unroll
        for (int j = 0; j < 4; ++j) {
          int lr = i * 16 + l4 * 4 + j;         // 0..31
          int lc = b * 16 + l15;
          VxB[(p * 32 + lr) * 64 + (lc ^ (((lr >> 2) & 3) << 4))] = bfc(acc[i][b][j]);
        }
  }
  __syncthreads();

  if (!isVar) {
    // finish region rows 0..31: M in regs, V from VxB
#pragma unroll
    for (int i = 0; i < 2; ++i)
#pragma unroll
      for (int b = 0; b < 4; ++b) {
        int col = colBase + wc * 64 + b * 16 + l15;
        float sc = scale[col], sh = shift[col];
#pragma unroll
        for (int j = 0; j < 4; ++j) {
          int lr = i * 16 + l4 * 4 + j;
          int lc = b * 16 + l15;
          float vv = bf2f(VxB[(p * 32 + lr) * 64 + (lc ^ (((lr >> 2) & 3) << 4))]);
          size_t idx = (size_t)(rowBase + wr * 64 + lr) * ODIM + col;
          out[idx] = fmaf(acc[i][b][j] + sqrtf(fmaxf(vv, 0.f)) * noise[idx], sc, sh);
        }
      }
  } else {
    // finish region rows 32..63: V in regs, M from MxB
#pragma unroll
    for (int i = 2; i < 4; ++i)
#pragma unroll
      for (int b = 0; b < 4; ++b) {
        int col = colBase + wc * 64 + b * 16 + l15;
        float sc = scale[col], sh = shift[col];
#pragma unroll
        for (int j = 0; j < 4; ++j) {
          int lr = (i - 2) * 16 + l4 * 4 + j;
          int lc = b * 16 + l15;
          float mm = bf2f(MxB[(p * 32 + lr) * 64 + (lc ^ (((lr >> 2) & 3) << 4))]);
          size_t idx = (size_t)(rowBase + wr * 64 + 32 + lr) * ODIM + col;
          out[idx] = fmaf(mm + sqrtf(fmaxf(acc[i][b][j], 0.f)) * noise[idx], sc, sh);
        }
      }
  }
}

// ---------------------------------------------------------------------------
extern "C" void kernel_launch(void* const* d_in, const int* in_sizes, int n_in,
                              void* d_out, int out_size, void* d_ws, size_t ws_size,
                              hipStream_t stream) {
  const float* x     = (const float*)d_in[0];   // [32768,1024]
  const float* wl    = (const float*)d_in[1];   // [1024,1024,2]
  const float* scale = (const float*)d_in[2];   // [1024]
  const float* shift = (const float*)d_in[3];   // [1024]
  const float* noise = (const float*)d_in[4];   // [32768,1024]
  float* out = (float*)d_out;

  unsigned short* wm  = (unsigned short*)d_ws;           // 2 MB
  unsigned short* wv  = wm + (size_t)ODIM * KDIM;        // 2 MB
  unsigned short* xbf = wv + (size_t)ODIM * KDIM;        // 64 MB

  const size_t need = 2ull * ODIM * KDIM * 2 + (size_t)N_TOK * KDIM * 2;
  const bool pre = (ws_size >= need);

  wprep_kernel<<<(ODIM * KDIM / 2) / 256, 256, 0, stream>>>(wl, wm, wv);
  if (pre)
    xprep_kernel<<<4096, 256, 0, stream>>>(x, xbf);

  // grid = (32768/128) * (1024/128) = 2048 blocks of 512 threads
  if (pre)
    ternary_gemm<true><<<2048, THREADS, 0, stream>>>(
        x, xbf, wm, wv, scale, shift, noise, out);
  else
    ternary_gemm<false><<<2048, THREADS, 0, stream>>>(
        x, xbf, wm, wv, scale, shift, noise, out);
}